// Round 11
// baseline (22.305 us; speedup 1.0000x reference)
//
#include <hip/hip_runtime.h>
#include <math.h>

#define N 512
#define C 256          // distinct label-diff classes per row (labels repeat)
#define D 128

// ---------------- K1: rank precompute (labels-only) + all-pairs logit tiles ----------------
// Block b: (a) ranks for label-row b: minrank = #{j: ld_j < ld_c}, fullrank adds
// ties with j<c (bijective 0..255). (b) R4-proven 32x32 logit tile.
__global__ __launch_bounds__(256) void k1_logits(const float* __restrict__ feat,
                                                 const float* __restrict__ labels,
                                                 float* __restrict__ lg,
                                                 int* __restrict__ ranks) {
    const int tid = threadIdx.x;
    const int b = blockIdx.x;

    // ---- rank section (1KB LDS, separate from tile buffers) ----
    __shared__ alignas(16) float sld[C];
    {
        const float2 lr = ((const float2*)labels)[b];
        const float2 lc = ((const float2*)labels)[tid];
        const float ldc = fabsf(lr.x - lc.x) + fabsf(lr.y - lc.y);   // bitwise ref expr
        sld[tid] = ldc;
        __syncthreads();
        int clt = 0, ceq = 0;
        const float4* s4 = (const float4*)sld;
#pragma unroll 8
        for (int q = 0; q < C / 4; ++q) {
            const float4 a = s4[q];          // wave-uniform LDS broadcast
            const int j0 = 4 * q;
            clt += (a.x < ldc); ceq += (a.x == ldc && (j0 + 0) < tid);
            clt += (a.y < ldc); ceq += (a.y == ldc && (j0 + 1) < tid);
            clt += (a.z < ldc); ceq += (a.z == ldc && (j0 + 2) < tid);
            clt += (a.w < ldc); ceq += (a.w == ldc && (j0 + 3) < tid);
        }
        ranks[b * C + tid] = (clt << 16) | (clt + ceq);   // minrank<<16 | fullrank
    }

    // ---- tile section (R4-proven body) ----
    const int row0 = (b >> 4) << 5;
    const int col0 = (b & 15) << 5;

    __shared__ float4 As[32][32];   // [row][swizzled q]
    __shared__ float4 Bs[32][32];

    const float4* f4 = (const float4*)feat;   // [512][32]
    {
        const int r = tid >> 5, c4 = tid & 31;
#pragma unroll
        for (int p = 0; p < 4; ++p) {
            const int rr = r + p * 8;
            const int sc = c4 ^ ((rr >> 1) & 7);
            As[rr][sc] = f4[(size_t)(row0 + rr) * 32 + c4];
            Bs[rr][sc] = f4[(size_t)(col0 + rr) * 32 + c4];
        }
    }
    __syncthreads();

    const int ty = tid >> 4, tx = tid & 15;
    const int r0 = 2 * ty, r1 = 2 * ty + 1;
    const int c0 = 2 * tx, c1 = 2 * tx + 1;
    const int sa = ty & 7, sb = tx & 7;

    float s00 = 0.f, s01 = 0.f, s10 = 0.f, s11 = 0.f;
#pragma unroll 8
    for (int q = 0; q < 32; ++q) {
        float4 a0 = As[r0][q ^ sa];
        float4 a1 = As[r1][q ^ sa];
        float4 b0 = Bs[c0][q ^ sb];
        float4 b1 = Bs[c1][q ^ sb];
        float t;
        t = a0.x - b0.x; s00 = fmaf(t, t, s00);
        t = a0.y - b0.y; s00 = fmaf(t, t, s00);
        t = a0.z - b0.z; s00 = fmaf(t, t, s00);
        t = a0.w - b0.w; s00 = fmaf(t, t, s00);
        t = a0.x - b1.x; s01 = fmaf(t, t, s01);
        t = a0.y - b1.y; s01 = fmaf(t, t, s01);
        t = a0.z - b1.z; s01 = fmaf(t, t, s01);
        t = a0.w - b1.w; s01 = fmaf(t, t, s01);
        t = a1.x - b0.x; s10 = fmaf(t, t, s10);
        t = a1.y - b0.y; s10 = fmaf(t, t, s10);
        t = a1.z - b0.z; s10 = fmaf(t, t, s10);
        t = a1.w - b0.w; s10 = fmaf(t, t, s10);
        t = a1.x - b1.x; s11 = fmaf(t, t, s11);
        t = a1.y - b1.y; s11 = fmaf(t, t, s11);
        t = a1.z - b1.z; s11 = fmaf(t, t, s11);
        t = a1.w - b1.w; s11 = fmaf(t, t, s11);
    }
    // safe_l2: identical rows give s == 0 exactly -> logit 0 (diagonal)
    float l00 = (s00 > 0.f) ? -0.5f * sqrtf(s00) : 0.f;
    float l01 = (s01 > 0.f) ? -0.5f * sqrtf(s01) : 0.f;
    float l10 = (s10 > 0.f) ? -0.5f * sqrtf(s10) : 0.f;
    float l11 = (s11 > 0.f) ? -0.5f * sqrtf(s11) : 0.f;

    *(float2*)(lg + (size_t)(row0 + r0) * N + col0 + c0) = make_float2(l00, l01);
    *(float2*)(lg + (size_t)(row0 + r1) * N + col0 + c0) = make_float2(l10, l11);
}

// ---------------- K23: per-row max/exp + rank-scatter + suffix-scan denominators ----------------
// Replaces the O(C^2) compare loop with: scatter sev to reversed-rank slot,
// 8-stage inclusive scan, read suffix at 255-minrank (no subtraction -> no
// cancellation for large-ld classes).
__global__ __launch_bounds__(256) void k23_row(const float* __restrict__ lg,
                                               const int* __restrict__ ranks,
                                               float* __restrict__ rowout) {
    const int i = blockIdx.x;
    const int c = threadIdx.x;

    __shared__ alignas(16) float sa_[C];   // scan ping
    __shared__ alignas(16) float sb_[C];   // scan pong
    __shared__ float redm[4], reds[4], redl[4];
    __shared__ float lci;

    const float la = lg[(size_t)i * N + c];
    const float lb = lg[(size_t)i * N + c + 256];

    // row max over j != i (lg[i][i] == 0 excluded)
    float m = -1e30f;
    if (c != i) m = la;
    if (c + 256 != i) m = fmaxf(m, lb);
#pragma unroll
    for (int off = 32; off > 0; off >>= 1) m = fmaxf(m, __shfl_xor(m, off, 64));
    if ((c & 63) == 0) redm[c >> 6] = m;
    __syncthreads();
    m = fmaxf(fmaxf(redm[0], redm[1]), fmaxf(redm[2], redm[3]));

    // exp values; diagonal forced to 0 drops it from every denominator
    const float ea = (c == i) ? 0.f : __expf(la - m);
    const float eb = (c + 256 == i) ? 0.f : __expf(lb - m);
    const float sev = ea + eb;

    const int pk = ranks[(size_t)(i & 255) * C + c];
    const int minrank  = pk >> 16;
    const int fullrank = pk & 0xffff;

    // scatter to reversed-rank slot (suffix-sum becomes prefix-sum)
    sa_[255 - fullrank] = sev;

    // rowsum = sum_{k != i}(lg_k - m) = (sum_k lg_k) - 511*m   (lg_i == 0)
    float s = la + lb;
#pragma unroll
    for (int off = 32; off > 0; off >>= 1) s += __shfl_xor(s, off, 64);
    if ((c & 63) == 0) reds[c >> 6] = s;
    __syncthreads();                       // publishes scatter + reds
    const float rowsum = (reds[0] + reds[1] + reds[2] + reds[3]) - 511.f * m;

    // 8-stage Hillis-Steele inclusive prefix scan (ping-pong)
    float* src = sa_;
    float* dst = sb_;
#pragma unroll
    for (int off = 1; off < C; off <<= 1) {
        float v = src[c];
        if (c >= off) v += src[c - off];
        dst[c] = v;
        __syncthreads();
        float* tmp = src; src = dst; dst = tmp;
    }
    // src holds the inclusive scan; den(c) = suffix-sum from minrank
    const float den  = src[255 - minrank];
    const float lden = __logf(den);

    if (c == (i & 255)) lci = lden;   // class(i): ld == 0 -> den == total ev sum
    float t = lden;
#pragma unroll
    for (int off = 32; off > 0; off >>= 1) t += __shfl_xor(t, off, 64);
    if ((c & 63) == 0) redl[c >> 6] = t;
    __syncthreads();
    if (c == 0) {
        const float tot = redl[0] + redl[1] + redl[2] + redl[3];
        rowout[i] = rowsum - (2.f * tot - lci);
    }
}

// ---------------- K4: final reduction ----------------
__global__ __launch_bounds__(256) void k4_reduce(const float* __restrict__ rowout,
                                                 float* __restrict__ out) {
    const int tid = threadIdx.x;
    double s = 0.0;
    for (int j = tid; j < N; j += 256) s += (double)rowout[j];
#pragma unroll
    for (int off = 32; off > 0; off >>= 1) s += __shfl_down(s, off, 64);
    __shared__ double sd[4];
    if ((tid & 63) == 0) sd[tid >> 6] = s;
    __syncthreads();
    if (tid == 0) {
        double t = sd[0] + sd[1] + sd[2] + sd[3];
        out[0] = (float)(-t / ((double)N * (double)(N - 1)));
    }
}

extern "C" void kernel_launch(void* const* d_in, const int* in_sizes, int n_in,
                              void* d_out, int out_size, void* d_ws, size_t ws_size,
                              hipStream_t stream) {
    const float* feat   = (const float*)d_in[0];   // [512,128] f32
    const float* labels = (const float*)d_in[1];   // [256,2]  f32
    float* out = (float*)d_out;

    float* lg     = (float*)d_ws;                  // N*N f32
    int*   ranks  = (int*)(lg + (size_t)N * N);    // 256*C int (minrank<<16|fullrank)
    float* rowout = (float*)(ranks + 256 * C);     // N f32

    k1_logits<<<256, 256, 0, stream>>>(feat, labels, lg, ranks);
    k23_row <<<N,   256, 0, stream>>>(lg, ranks, rowout);
    k4_reduce<<<1,  256, 0, stream>>>(rowout, out);
}

// Round 12
// 19.864 us; speedup vs baseline: 1.1229x; 1.1229x over previous
//
#include <hip/hip_runtime.h>
#include <math.h>

#define N 512
#define C 256          // distinct label-diff classes per row (labels repeat)
#define D 128
#define NG 8           // tail groups (64 rows each)
#define GSTRIDE 32     // floats between group pairs -> separate 128B lines

// ---------------- K1: all-pairs logits via LDS-staged 32x32 tiles + ld2 rows (+ tail reset) ----------------
__global__ __launch_bounds__(256) void k1_logits(const float* __restrict__ feat,
                                                 const float* __restrict__ labels,
                                                 float* __restrict__ lg,
                                                 float* __restrict__ ld2,
                                                 float* __restrict__ tail) {
    const int tid = threadIdx.x;

    // reset hierarchical-tail state (one node upstream of use: stream order makes this replay-safe)
    if (blockIdx.x == 0 && tid < NG + 1) {
        float*    a = tail + tid * GSTRIDE;
        unsigned* c = (unsigned*)(a + 1);
        __hip_atomic_store(a, 0.f, __ATOMIC_RELAXED, __HIP_MEMORY_SCOPE_AGENT);
        __hip_atomic_store(c, 0u,  __ATOMIC_RELAXED, __HIP_MEMORY_SCOPE_AGENT);
    }

    // ld2 rows 2b and 2b+1 (labels-only; K23 reads it via cross-kernel s_load path)
    {
        const int i0 = blockIdx.x << 1;
#pragma unroll
        for (int e = tid; e < 2 * C; e += 256) {
            const int row = i0 + (e >> 8);
            const int cc  = e & 255;
            const float2 lc2 = ((const float2*)labels)[cc];
            const float2 li2 = ((const float2*)labels)[row & 255];
            ld2[(size_t)row * C + cc] = fabsf(li2.x - lc2.x) + fabsf(li2.y - lc2.y);
        }
    }

    const int row0 = (blockIdx.x >> 4) << 5;
    const int col0 = (blockIdx.x & 15) << 5;

    __shared__ float4 As[32][32];   // [row][swizzled q]
    __shared__ float4 Bs[32][32];

    const float4* f4 = (const float4*)feat;   // [512][32]
    {
        const int r = tid >> 5, c4 = tid & 31;
#pragma unroll
        for (int p = 0; p < 4; ++p) {
            const int rr = r + p * 8;
            const int sc = c4 ^ ((rr >> 1) & 7);
            As[rr][sc] = f4[(size_t)(row0 + rr) * 32 + c4];
            Bs[rr][sc] = f4[(size_t)(col0 + rr) * 32 + c4];
        }
    }
    __syncthreads();

    const int ty = tid >> 4, tx = tid & 15;
    const int r0 = 2 * ty, r1 = 2 * ty + 1;
    const int c0 = 2 * tx, c1 = 2 * tx + 1;
    const int sa = ty & 7, sb = tx & 7;

    float s00 = 0.f, s01 = 0.f, s10 = 0.f, s11 = 0.f;
#pragma unroll 8
    for (int q = 0; q < 32; ++q) {
        float4 a0 = As[r0][q ^ sa];
        float4 a1 = As[r1][q ^ sa];
        float4 b0 = Bs[c0][q ^ sb];
        float4 b1 = Bs[c1][q ^ sb];
        float t;
        t = a0.x - b0.x; s00 = fmaf(t, t, s00);
        t = a0.y - b0.y; s00 = fmaf(t, t, s00);
        t = a0.z - b0.z; s00 = fmaf(t, t, s00);
        t = a0.w - b0.w; s00 = fmaf(t, t, s00);
        t = a0.x - b1.x; s01 = fmaf(t, t, s01);
        t = a0.y - b1.y; s01 = fmaf(t, t, s01);
        t = a0.z - b1.z; s01 = fmaf(t, t, s01);
        t = a0.w - b1.w; s01 = fmaf(t, t, s01);
        t = a1.x - b0.x; s10 = fmaf(t, t, s10);
        t = a1.y - b0.y; s10 = fmaf(t, t, s10);
        t = a1.z - b0.z; s10 = fmaf(t, t, s10);
        t = a1.w - b0.w; s10 = fmaf(t, t, s10);
        t = a1.x - b1.x; s11 = fmaf(t, t, s11);
        t = a1.y - b1.y; s11 = fmaf(t, t, s11);
        t = a1.z - b1.z; s11 = fmaf(t, t, s11);
        t = a1.w - b1.w; s11 = fmaf(t, t, s11);
    }
    // safe_l2: identical rows give s == 0 exactly -> logit 0 (diagonal)
    float l00 = (s00 > 0.f) ? -0.5f * sqrtf(s00) : 0.f;
    float l01 = (s01 > 0.f) ? -0.5f * sqrtf(s01) : 0.f;
    float l10 = (s10 > 0.f) ? -0.5f * sqrtf(s10) : 0.f;
    float l11 = (s11 > 0.f) ? -0.5f * sqrtf(s11) : 0.f;

    *(float2*)(lg + (size_t)(row0 + r0) * N + col0 + c0) = make_float2(l00, l01);
    *(float2*)(lg + (size_t)(row0 + r1) * N + col0 + c0) = make_float2(l10, l11);
}

// ---------------- K23: fused per-row loss (R10-proven body) + hierarchical fence-free tail ----------------
__global__ __launch_bounds__(256) void k23_row(const float* __restrict__ lg,
                                               const float* __restrict__ ld2,
                                               float* __restrict__ tail,
                                               float* __restrict__ out) {
    const int i = blockIdx.x;
    const int c = threadIdx.x;

    __shared__ alignas(16) float sev[C];
    __shared__ float redm[4], reds[4], redl[4];
    __shared__ float lci;

    const float la = lg[(size_t)i * N + c];
    const float lb = lg[(size_t)i * N + c + 256];

    // row max over j != i (lg[i][i] == 0 excluded)
    float m = -1e30f;
    if (c != i) m = la;
    if (c + 256 != i) m = fmaxf(m, lb);
#pragma unroll
    for (int off = 32; off > 0; off >>= 1) m = fmaxf(m, __shfl_xor(m, off, 64));
    if ((c & 63) == 0) redm[c >> 6] = m;
    __syncthreads();
    m = fmaxf(fmaxf(redm[0], redm[1]), fmaxf(redm[2], redm[3]));

    // exp values; diagonal forced to 0 drops it from every denominator
    const float ea = (c == i) ? 0.f : __expf(la - m);
    const float eb = (c + 256 == i) ? 0.f : __expf(lb - m);
    sev[c] = ea + eb;

    // rowsum = sum_{k != i}(lg_k - m) = (sum_k lg_k) - 511*m   (lg_i == 0)
    float s = la + lb;
#pragma unroll
    for (int off = 32; off > 0; off >>= 1) s += __shfl_xor(s, off, 64);
    if ((c & 63) == 0) reds[c >> 6] = s;
    __syncthreads();                       // publishes sev + reds
    const float rowsum = (reds[0] + reds[1] + reds[2] + reds[3]) - 511.f * m;

    // denominator: ld2 via wave-uniform scalar loads (s_load path, written by K1),
    // sev via single-stream LDS float4 broadcasts. (R10-proven fast.)
    const float* __restrict__ rl = ld2 + (size_t)i * C;
    const float ldk = rl[c];
    const float4* e4 = (const float4*)sev;
    float d0 = 0.f, d1 = 0.f, d2 = 0.f, d3 = 0.f;
#pragma unroll 8
    for (int q = 0; q < C / 4; ++q) {
        const float a0 = rl[4 * q + 0], a1 = rl[4 * q + 1];
        const float a2 = rl[4 * q + 2], a3 = rl[4 * q + 3];
        const float4 ev = e4[q];
        d0 += (a0 >= ldk) ? ev.x : 0.f;
        d1 += (a1 >= ldk) ? ev.y : 0.f;
        d2 += (a2 >= ldk) ? ev.z : 0.f;
        d3 += (a3 >= ldk) ? ev.w : 0.f;
    }
    const float lden = __logf((d0 + d1) + (d2 + d3));

    if (c == (i & 255)) lci = lden;   // class(i): ld == 0 -> den == total ev sum
    float t = lden;
#pragma unroll
    for (int off = 32; off > 0; off >>= 1) t += __shfl_xor(t, off, 64);
    if ((c & 63) == 0) redl[c >> 6] = t;
    __syncthreads();

    if (c == 0) {
        const float tot  = redl[0] + redl[1] + redl[2] + redl[3];
        const float part = rowsum - (2.f * tot - lci);

        // ---- hierarchical fence-free last-arriver (R8/R9-proven protocol) ----
        // Level 1: 8 groups x 64 rows; each group's (acc,cnt) on its own 128B line,
        // chains run in parallel. ack(acc RMW) BEFORE cnt RMW => cnt==64 implies
        // all 64 acc-adds complete at the coherence point.
        const int g = i >> 6;
        float*    gacc = tail + g * GSTRIDE;
        unsigned* gcnt = (unsigned*)(gacc + 1);
        float r = __hip_atomic_fetch_add(gacc, part, __ATOMIC_RELAXED, __HIP_MEMORY_SCOPE_AGENT);
        __asm__ volatile("" :: "v"(r));
        const unsigned prev = __hip_atomic_fetch_add(gcnt, 1u, __ATOMIC_RELAXED,
                                                     __HIP_MEMORY_SCOPE_AGENT);
        if (prev == 63u) {                 // group-last: fold group sum into level 2
            const float gsum = __hip_atomic_load(gacc, __ATOMIC_RELAXED, __HIP_MEMORY_SCOPE_AGENT);
            float*    acc2 = tail + NG * GSTRIDE;
            unsigned* cnt2 = (unsigned*)(acc2 + 1);
            float r2 = __hip_atomic_fetch_add(acc2, gsum, __ATOMIC_RELAXED, __HIP_MEMORY_SCOPE_AGENT);
            __asm__ volatile("" :: "v"(r2));
            const unsigned p2 = __hip_atomic_fetch_add(cnt2, 1u, __ATOMIC_RELAXED,
                                                       __HIP_MEMORY_SCOPE_AGENT);
            if (p2 == (unsigned)(NG - 1)) {   // global last
                const float total = __hip_atomic_load(acc2, __ATOMIC_RELAXED,
                                                      __HIP_MEMORY_SCOPE_AGENT);
                out[0] = -total / ((float)N * (float)(N - 1));
            }
        }
    }
}

extern "C" void kernel_launch(void* const* d_in, const int* in_sizes, int n_in,
                              void* d_out, int out_size, void* d_ws, size_t ws_size,
                              hipStream_t stream) {
    const float* feat   = (const float*)d_in[0];   // [512,128] f32
    const float* labels = (const float*)d_in[1];   // [256,2]  f32
    float* out = (float*)d_out;

    float* lg   = (float*)d_ws;                    // N*N
    float* ld2  = lg + (size_t)N * N;              // N*C
    float* tail = ld2 + (size_t)N * C;             // (NG+1)*GSTRIDE floats

    k1_logits<<<256, 256, 0, stream>>>(feat, labels, lg, ld2, tail);
    k23_row <<<N,   256, 0, stream>>>(lg, ld2, tail, out);
}

// Round 13
// 19.376 us; speedup vs baseline: 1.1512x; 1.0252x over previous
//
#include <hip/hip_runtime.h>
#include <math.h>

#define N 512
#define C 256          // distinct label-diff classes per row (labels repeat)
#define D 128

// ---------------- K1: all-pairs logits via LDS-staged 32x32 tiles + ld2 rows ----------------
// ld2 depends only on labels, so it's produced here; K23 then reads it via the
// cross-kernel scalar-load path (R4-proven fast).
__global__ __launch_bounds__(256) void k1_logits(const float* __restrict__ feat,
                                                 const float* __restrict__ labels,
                                                 float* __restrict__ lg,
                                                 float* __restrict__ ld2) {
    const int tid = threadIdx.x;

    // ld2 rows 2b and 2b+1 (512 elems, 2 per thread) — bitwise same expression as reference
    {
        const int i0 = blockIdx.x << 1;
#pragma unroll
        for (int e = tid; e < 2 * C; e += 256) {
            const int row = i0 + (e >> 8);
            const int cc  = e & 255;
            const float2 lc2 = ((const float2*)labels)[cc];
            const float2 li2 = ((const float2*)labels)[row & 255];
            ld2[(size_t)row * C + cc] = fabsf(li2.x - lc2.x) + fabsf(li2.y - lc2.y);
        }
    }

    const int row0 = (blockIdx.x >> 4) << 5;
    const int col0 = (blockIdx.x & 15) << 5;

    __shared__ float4 As[32][32];   // [row][swizzled q]
    __shared__ float4 Bs[32][32];

    const float4* f4 = (const float4*)feat;   // [512][32]
    {
        const int r = tid >> 5, c4 = tid & 31;
#pragma unroll
        for (int p = 0; p < 4; ++p) {
            const int rr = r + p * 8;
            const int sc = c4 ^ ((rr >> 1) & 7);
            As[rr][sc] = f4[(size_t)(row0 + rr) * 32 + c4];
            Bs[rr][sc] = f4[(size_t)(col0 + rr) * 32 + c4];
        }
    }
    __syncthreads();

    const int ty = tid >> 4, tx = tid & 15;
    const int r0 = 2 * ty, r1 = 2 * ty + 1;
    const int c0 = 2 * tx, c1 = 2 * tx + 1;
    const int sa = ty & 7, sb = tx & 7;

    float s00 = 0.f, s01 = 0.f, s10 = 0.f, s11 = 0.f;
#pragma unroll 8
    for (int q = 0; q < 32; ++q) {
        float4 a0 = As[r0][q ^ sa];
        float4 a1 = As[r1][q ^ sa];
        float4 b0 = Bs[c0][q ^ sb];
        float4 b1 = Bs[c1][q ^ sb];
        float t;
        t = a0.x - b0.x; s00 = fmaf(t, t, s00);
        t = a0.y - b0.y; s00 = fmaf(t, t, s00);
        t = a0.z - b0.z; s00 = fmaf(t, t, s00);
        t = a0.w - b0.w; s00 = fmaf(t, t, s00);
        t = a0.x - b1.x; s01 = fmaf(t, t, s01);
        t = a0.y - b1.y; s01 = fmaf(t, t, s01);
        t = a0.z - b1.z; s01 = fmaf(t, t, s01);
        t = a0.w - b1.w; s01 = fmaf(t, t, s01);
        t = a1.x - b0.x; s10 = fmaf(t, t, s10);
        t = a1.y - b0.y; s10 = fmaf(t, t, s10);
        t = a1.z - b0.z; s10 = fmaf(t, t, s10);
        t = a1.w - b0.w; s10 = fmaf(t, t, s10);
        t = a1.x - b1.x; s11 = fmaf(t, t, s11);
        t = a1.y - b1.y; s11 = fmaf(t, t, s11);
        t = a1.z - b1.z; s11 = fmaf(t, t, s11);
        t = a1.w - b1.w; s11 = fmaf(t, t, s11);
    }
    // safe_l2: identical rows give s == 0 exactly -> logit 0 (diagonal)
    float l00 = (s00 > 0.f) ? -0.5f * sqrtf(s00) : 0.f;
    float l01 = (s01 > 0.f) ? -0.5f * sqrtf(s01) : 0.f;
    float l10 = (s10 > 0.f) ? -0.5f * sqrtf(s10) : 0.f;
    float l11 = (s11 > 0.f) ? -0.5f * sqrtf(s11) : 0.f;

    *(float2*)(lg + (size_t)(row0 + r0) * N + col0 + c0) = make_float2(l00, l01);
    *(float2*)(lg + (size_t)(row0 + r1) * N + col0 + c0) = make_float2(l10, l11);
}

// ---------------- K23: fused per-row max/exp/denominator/loss (no atomics) ----------------
// Denominator loop: compare operand from cross-kernel ld2 (wave-uniform scalar
// reads -> s_load), exp values from in-kernel LDS broadcast (single LDS stream).
__global__ __launch_bounds__(256) void k23_row(const float* __restrict__ lg,
                                               const float* __restrict__ ld2,
                                               float* __restrict__ rowout) {
    const int i = blockIdx.x;
    const int c = threadIdx.x;

    __shared__ alignas(16) float sev[C];
    __shared__ float redm[4], reds[4], redl[4];
    __shared__ float lci;

    const float la = lg[(size_t)i * N + c];
    const float lb = lg[(size_t)i * N + c + 256];

    // row max over j != i (lg[i][i] == 0 excluded)
    float m = -1e30f;
    if (c != i) m = la;
    if (c + 256 != i) m = fmaxf(m, lb);
#pragma unroll
    for (int off = 32; off > 0; off >>= 1) m = fmaxf(m, __shfl_xor(m, off, 64));
    if ((c & 63) == 0) redm[c >> 6] = m;
    __syncthreads();
    m = fmaxf(fmaxf(redm[0], redm[1]), fmaxf(redm[2], redm[3]));

    // exp values; diagonal forced to 0 drops it from every denominator
    const float ea = (c == i) ? 0.f : __expf(la - m);
    const float eb = (c + 256 == i) ? 0.f : __expf(lb - m);
    sev[c] = ea + eb;

    // rowsum = sum_{k != i}(lg_k - m) = (sum_k lg_k) - 511*m   (lg_i == 0)
    float s = la + lb;
#pragma unroll
    for (int off = 32; off > 0; off >>= 1) s += __shfl_xor(s, off, 64);
    if ((c & 63) == 0) reds[c >> 6] = s;
    __syncthreads();                       // publishes sev + reds
    const float rowsum = (reds[0] + reds[1] + reds[2] + reds[3]) - 511.f * m;

    // denominator: ld2 via wave-uniform scalar loads (s_load path, written by K1),
    // sev via single-stream LDS float4 broadcasts.
    const float* __restrict__ rl = ld2 + (size_t)i * C;
    const float ldk = rl[c];
    const float4* e4 = (const float4*)sev;
    float d0 = 0.f, d1 = 0.f, d2 = 0.f, d3 = 0.f;
#pragma unroll 8
    for (int q = 0; q < C / 4; ++q) {
        const float a0 = rl[4 * q + 0], a1 = rl[4 * q + 1];
        const float a2 = rl[4 * q + 2], a3 = rl[4 * q + 3];
        const float4 ev = e4[q];
        d0 += (a0 >= ldk) ? ev.x : 0.f;
        d1 += (a1 >= ldk) ? ev.y : 0.f;
        d2 += (a2 >= ldk) ? ev.z : 0.f;
        d3 += (a3 >= ldk) ? ev.w : 0.f;
    }
    const float lden = __logf((d0 + d1) + (d2 + d3));

    if (c == (i & 255)) lci = lden;   // class(i): ld == 0 -> den == total ev sum
    float t = lden;
#pragma unroll
    for (int off = 32; off > 0; off >>= 1) t += __shfl_xor(t, off, 64);
    if ((c & 63) == 0) redl[c >> 6] = t;
    __syncthreads();
    if (c == 0) {
        const float tot = redl[0] + redl[1] + redl[2] + redl[3];
        rowout[i] = rowsum - (2.f * tot - lci);
    }
}

// ---------------- K4: final reduction ----------------
__global__ __launch_bounds__(256) void k4_reduce(const float* __restrict__ rowout,
                                                 float* __restrict__ out) {
    const int tid = threadIdx.x;
    double s = 0.0;
    for (int j = tid; j < N; j += 256) s += (double)rowout[j];
#pragma unroll
    for (int off = 32; off > 0; off >>= 1) s += __shfl_down(s, off, 64);
    __shared__ double sd[4];
    if ((tid & 63) == 0) sd[tid >> 6] = s;
    __syncthreads();
    if (tid == 0) {
        double t = sd[0] + sd[1] + sd[2] + sd[3];
        out[0] = (float)(-t / ((double)N * (double)(N - 1)));
    }
}

extern "C" void kernel_launch(void* const* d_in, const int* in_sizes, int n_in,
                              void* d_out, int out_size, void* d_ws, size_t ws_size,
                              hipStream_t stream) {
    const float* feat   = (const float*)d_in[0];   // [512,128] f32
    const float* labels = (const float*)d_in[1];   // [256,2]  f32
    float* out = (float*)d_out;

    float* lg     = (float*)d_ws;                  // N*N
    float* ld2    = lg + (size_t)N * N;            // N*C
    float* rowout = ld2 + (size_t)N * C;           // N

    k1_logits<<<256, 256, 0, stream>>>(feat, labels, lg, ld2);
    k23_row <<<N,   256, 0, stream>>>(lg, ld2, rowout);
    k4_reduce<<<1,  256, 0, stream>>>(rowout, out);
}